// Round 6
// baseline (986.655 us; speedup 1.0000x reference)
//
#include <hip/hip_runtime.h>

#define N_NODES 100000
#define N_EDGES 1600000
#define MAXD 64

typedef unsigned int u32;
typedef unsigned short u16;

__device__ __forceinline__ float bf2f(u16 u){ return __uint_as_float(((u32)u) << 16); }
__device__ __forceinline__ float lo16(u32 u){ return __uint_as_float(u << 16); }
__device__ __forceinline__ float hi16(u32 u){ return __uint_as_float(u & 0xffff0000u); }
__device__ __forceinline__ u32 f2bfbits(float f){
  u32 u = __float_as_uint(f);
  return (u + 0x7fffu + ((u >> 16) & 1u)) >> 16;
}

// GELU with pure-FMA erf: erf(z) = z*P(z^2), 7-term Taylor, |err|<=7e-9 for
// |z|<=0.6 (data has |z| <~ 0.53 at 6 sigma). Per-lane erff fallback for
// |z|>0.6 keeps exactness on any input (never taken here => no trans ops on
// the hot path; round-3 lesson: rcp/exp are quarter-rate, avoid them).
__device__ __forceinline__ float gelu_fast(float h){
  float z = h * 0.70710678118654752f;
  float u = z * z;
  const float k0 = 1.1283791670955126f;
  const float k1 = -0.37612638903183752f;
  const float k2 = 0.11283791670955126f;
  const float k3 = -0.026866170645131251f;
  const float k4 = 0.0052239776254421878f;
  const float k5 = -8.5483270234508528e-4f;
  const float k6 = 1.2055332981789664e-4f;
  float p = __builtin_fmaf(k6, u, k5);
  p = __builtin_fmaf(p, u, k4);
  p = __builtin_fmaf(p, u, k3);
  p = __builtin_fmaf(p, u, k2);
  p = __builtin_fmaf(p, u, k1);
  p = __builtin_fmaf(p, u, k0);
  float er = z * p;
  if (u > 0.36f) er = erff(z);      // exact tail, wave-coherently skipped
  float hh = 0.5f * h;
  return __builtin_fmaf(hh, er, hh);
}

// DT=1: fp32 buffers, DT=0: bf16 buffers
template<int DT>
__device__ __forceinline__ float ldf(const void* p, size_t i){
  if (DT) return ((const float*)p)[i];
  else    return bf2f(((const u16*)p)[i]);
}

// flags[0]: 1 if edge_index is int64, 0 if int32
// flags[1]: 1 if float tensors are fp32, 0 if bf16
__device__ __forceinline__ int ld_src(const int* ei, int e, int f64){
  return f64 ? ei[2*(size_t)e] : ei[e];
}
__device__ __forceinline__ int ld_tgt(const int* ei, int e, int f64){
  return f64 ? ei[2*((size_t)N_EDGES + (size_t)e)] : ei[(size_t)N_EDGES + e];
}

__device__ __forceinline__ float bfdot16(uint4 qa, uint4 qb, uint4 ka, uint4 kb){
  float s = 0.f;
  s += lo16(qa.x)*lo16(ka.x) + hi16(qa.x)*hi16(ka.x);
  s += lo16(qa.y)*lo16(ka.y) + hi16(qa.y)*hi16(ka.y);
  s += lo16(qa.z)*lo16(ka.z) + hi16(qa.z)*hi16(ka.z);
  s += lo16(qa.w)*lo16(ka.w) + hi16(qa.w)*hi16(ka.w);
  s += lo16(qb.x)*lo16(kb.x) + hi16(qb.x)*hi16(kb.x);
  s += lo16(qb.y)*lo16(kb.y) + hi16(qb.y)*hi16(kb.y);
  s += lo16(qb.z)*lo16(kb.z) + hi16(qb.z)*hi16(kb.z);
  s += lo16(qb.w)*lo16(kb.w) + hi16(qb.w)*hi16(kb.w);
  return s;
}

extern "C" __global__ void detect_kernel(const int* __restrict__ ei,
                                         const u32* __restrict__ xw,
                                         int* __restrict__ flags)
{
  if (blockIdx.x == 0 && threadIdx.x == 0) {
    int any = 0;
    #pragma unroll
    for (int i = 0; i < 32; ++i) any |= ei[2*i + 1];
    flags[0] = (any == 0) ? 1 : 0;
    int weird = 0;
    for (int i = 0; i < 256; ++i) {
      u32 w = xw[i];
      float a = lo16(w), b = hi16(w);
      if (!(fabsf(a) < 1024.f)) weird++;
      if (!(fabsf(b) < 1024.f)) weird++;
    }
    flags[1] = (weird > 0) ? 1 : 0;
  }
}

// ---------------- K1: QKV projection (x @ W -> bf16) ------------------------
template<int DT>
__global__ __launch_bounds__(256) void qkv_gemm_t(
    const void* __restrict__ x, const void* __restrict__ Wq,
    const void* __restrict__ Wk, const void* __restrict__ Wv,
    u16* __restrict__ Q, u16* __restrict__ Kd, u16* __restrict__ Vd,
    const int* __restrict__ flags)
{
  if (flags[1] != DT) return;
  __shared__ float xs[64*129];
  const int tid = threadIdx.x;
  const int row0 = blockIdx.x * 64;
  const void* W = (blockIdx.y == 0) ? Wq : (blockIdx.y == 1) ? Wk : Wv;
  u16* Out = (blockIdx.y == 0) ? Q : (blockIdx.y == 1) ? Kd : Vd;

  if (DT) {
    const float4* xg = (const float4*)x;
    #pragma unroll
    for (int i = 0; i < 8; ++i) {
      int li = tid + i*256;           // 64 rows x 32 float4
      int r = li >> 5, c4 = li & 31;
      float4 v = make_float4(0.f,0.f,0.f,0.f);
      if (row0 + r < N_NODES) v = xg[(size_t)(row0 + r)*32 + c4];
      int base = r*129 + c4*4;
      xs[base] = v.x; xs[base+1] = v.y; xs[base+2] = v.z; xs[base+3] = v.w;
    }
  } else {
    const uint4* xg = (const uint4*)x;
    #pragma unroll
    for (int i = 0; i < 4; ++i) {
      int li = tid + i*256;           // 64 rows x 16 uint4
      int r = li >> 4, c8 = li & 15;
      uint4 v = make_uint4(0,0,0,0);
      if (row0 + r < N_NODES) v = xg[(size_t)(row0 + r)*16 + c8];
      int base = r*129 + c8*8;
      xs[base+0]=lo16(v.x); xs[base+1]=hi16(v.x);
      xs[base+2]=lo16(v.y); xs[base+3]=hi16(v.y);
      xs[base+4]=lo16(v.z); xs[base+5]=hi16(v.z);
      xs[base+6]=lo16(v.w); xs[base+7]=hi16(v.w);
    }
  }
  __syncthreads();

  const int cg = tid & 31;
  const int r0 = (tid >> 5) * 8;
  float acc[8][4];
  #pragma unroll
  for (int i=0;i<8;++i){ acc[i][0]=0.f; acc[i][1]=0.f; acc[i][2]=0.f; acc[i][3]=0.f; }

  for (int k = 0; k < 128; ++k) {
    float4 b;
    if (DT) {
      b = ((const float4*)W)[k*32 + cg];
    } else {
      uint2 t = ((const uint2*)W)[k*32 + cg];
      b = make_float4(lo16(t.x), hi16(t.x), lo16(t.y), hi16(t.y));
    }
    #pragma unroll
    for (int i = 0; i < 8; ++i) {
      float a = xs[(r0+i)*129 + k];
      acc[i][0] += a*b.x; acc[i][1] += a*b.y; acc[i][2] += a*b.z; acc[i][3] += a*b.w;
    }
  }
  #pragma unroll
  for (int i = 0; i < 8; ++i) {
    int gr = row0 + r0 + i;
    if (gr < N_NODES) {
      u32 p0 = f2bfbits(acc[i][0]) | (f2bfbits(acc[i][1]) << 16);
      u32 p1 = f2bfbits(acc[i][2]) | (f2bfbits(acc[i][3]) << 16);
      ((uint2*)(Out + (size_t)gr*128))[cg] = make_uint2(p0, p1);
    }
  }
}

// -------- K2a: per-edge MLP bias -> scores (pure compute, no gathers) -------
// 2 edges/thread (round-4: VGPR 28, no spills, VALUBusy ~100%).
template<int DT>
__global__ __launch_bounds__(256) void bias_kernel_t(
    const void* __restrict__ ea,
    const void* __restrict__ We1, const void* __restrict__ be1,
    const void* __restrict__ We2, const void* __restrict__ be2,
    float* __restrict__ scores, const int* __restrict__ flags)
{
  if (flags[1] != DT) return;
  __shared__ __align__(16) float wpk[128][16]; // {be1, We1[0..5][j], pad, We2[j][0..7]}
  __shared__ float b2s[8];
  const int tid = threadIdx.x;
  if (tid < 128) {
    int j = tid;
    wpk[j][0] = ldf<DT>(be1, j);
    #pragma unroll
    for (int d = 0; d < 6; ++d) wpk[j][1+d] = ldf<DT>(We1, d*128 + j);
    wpk[j][7] = 0.f;
    #pragma unroll
    for (int h = 0; h < 8; ++h) wpk[j][8+h] = ldf<DT>(We2, j*8 + h);
  }
  if (tid < 8) b2s[tid] = ldf<DT>(be2, tid);
  __syncthreads();

  const int gid = blockIdx.x * 256 + tid;
  if (gid >= N_EDGES/2) return;
  const int e0 = gid * 2;

  float a[12];
  if (DT) {
    const float4* eg = (const float4*)ea + (size_t)gid*3;   // 2 edges = 12 floats
    float4 v0 = eg[0], v1 = eg[1], v2 = eg[2];
    a[0]=v0.x; a[1]=v0.y; a[2]=v0.z; a[3]=v0.w;
    a[4]=v1.x; a[5]=v1.y; a[6]=v1.z; a[7]=v1.w;
    a[8]=v2.x; a[9]=v2.y; a[10]=v2.z; a[11]=v2.w;
  } else {
    const uint2* eg = (const uint2*)ea + (size_t)gid*3;     // 2 edges = 12 bf16 = 24B
    uint2 v0 = eg[0], v1 = eg[1], v2 = eg[2];
    u32 d[6] = {v0.x, v0.y, v1.x, v1.y, v2.x, v2.y};
    #pragma unroll
    for (int idx = 0; idx < 12; ++idx)
      a[idx] = (idx & 1) ? hi16(d[idx >> 1]) : lo16(d[idx >> 1]);
  }

  float bias[2][8];
  #pragma unroll
  for (int t=0;t<2;++t)
    #pragma unroll
    for (int h=0;h<8;++h) bias[t][h] = b2s[h];

  for (int j = 0; j < 128; ++j) {
    const float4* wp = (const float4*)wpk[j];
    float4 p0 = wp[0], p1 = wp[1], p2 = wp[2], p3 = wp[3];
    #pragma unroll
    for (int t = 0; t < 2; ++t) {
      float h = p0.x + a[t*6+0]*p0.y + a[t*6+1]*p0.z + a[t*6+2]*p0.w
                     + a[t*6+3]*p1.x + a[t*6+4]*p1.y + a[t*6+5]*p1.z;
      float g = gelu_fast(h);
      bias[t][0] += g*p2.x; bias[t][1] += g*p2.y; bias[t][2] += g*p2.z; bias[t][3] += g*p2.w;
      bias[t][4] += g*p3.x; bias[t][5] += g*p3.y; bias[t][6] += g*p3.z; bias[t][7] += g*p3.w;
    }
  }

  #pragma unroll
  for (int t = 0; t < 2; ++t) {
    float4* so = (float4*)(scores + (size_t)(e0 + t)*8);
    so[0] = make_float4(bias[t][0],bias[t][1],bias[t][2],bias[t][3]);
    so[1] = make_float4(bias[t][4],bias[t][5],bias[t][6],bias[t][7]);
  }
}

// ---------------- CSR build: histogram, scan, fill --------------------------
extern "C" __global__ __launch_bounds__(256) void hist_kernel(
    const int* __restrict__ ei, int* __restrict__ offs, const int* __restrict__ flags)
{
  int e = blockIdx.x*256 + threadIdx.x;
  if (e >= N_EDGES) return;
  int t = ld_tgt(ei, e, flags[0]);
  atomicAdd(&offs[t], 1);
}

extern "C" __global__ __launch_bounds__(1024) void scan1_kernel(
    int* __restrict__ offs, int* __restrict__ bsums)
{
  __shared__ int tmp[1024];
  int tid = threadIdx.x;
  int i = blockIdx.x*1024 + tid;
  int v = (i < N_NODES) ? offs[i] : 0;
  tmp[tid] = v;
  __syncthreads();
  for (int d = 1; d < 1024; d <<= 1) {
    int t = (tid >= d) ? tmp[tid-d] : 0;
    __syncthreads();
    tmp[tid] += t;
    __syncthreads();
  }
  if (i < N_NODES) offs[i] = tmp[tid] - v;   // block-exclusive
  if (tid == 1023) bsums[blockIdx.x] = tmp[1023];
}

extern "C" __global__ void scan2_kernel(int* __restrict__ bsums, int nb)
{
  if (threadIdx.x == 0 && blockIdx.x == 0) {
    int run = 0;
    for (int i = 0; i < nb; ++i) { int t = bsums[i]; bsums[i] = run; run += t; }
  }
}

extern "C" __global__ __launch_bounds__(1024) void scan3_kernel(
    int* __restrict__ offs, const int* __restrict__ bsums)
{
  int i = blockIdx.x*1024 + threadIdx.x;
  if (i < N_NODES) offs[i] += bsums[blockIdx.x];
}

extern "C" __global__ __launch_bounds__(256) void fill_kernel(
    const int* __restrict__ ei, int* __restrict__ offs,
    int* __restrict__ edge_sorted, const int* __restrict__ flags)
{
  int e = blockIdx.x*256 + threadIdx.x;
  if (e >= N_EDGES) return;
  int t = ld_tgt(ei, e, flags[0]);
  int p = atomicAdd(&offs[t], 1);
  edge_sorted[p] = e;
}

// ------ K3a: fused QK-dot + bias + online softmax + weight emit -------------
extern "C" __global__ __launch_bounds__(256) void node_score_kernel(
    const int* __restrict__ ei, const int* __restrict__ offs_incl,
    const int* __restrict__ edge_sorted, float* __restrict__ scores,
    const u16* __restrict__ Q, const u16* __restrict__ Kd,
    void* __restrict__ dout, const int* __restrict__ flags)
{
  __shared__ float s_lds[4][MAXD*8];
  __shared__ int   e_lds[4][MAXD];
  const int wid  = threadIdx.x >> 6;
  const int lane = threadIdx.x & 63;
  const int n = blockIdx.x*4 + wid;
  if (n >= N_NODES) return;
  const int f64 = flags[0], dt = flags[1];
  const int start = (n == 0) ? 0 : offs_incl[n-1];
  const int deg = offs_incl[n] - start;
  if (deg == 0) return;
  const int h = lane & 7, j = lane >> 3;

  // Q fragment for head h (32B, broadcast among the 8 lanes sharing h)
  const uint4* qr = (const uint4*)(Q + (size_t)n*128 + h*16);
  uint4 qa = qr[0], qb = qr[1];

  float m = -3.0e38f, s = 0.f;
  for (int jj = j; jj < deg; jj += 8) {
    int e = edge_sorted[start + jj];
    int src = ld_src(ei, e, f64);
    const uint4* kr = (const uint4*)(Kd + (size_t)src*128 + h*16);
    uint4 ka = kr[0], kb = kr[1];
    float v = bfdot16(qa, qb, ka, kb) * 0.25f + scores[(size_t)e*8 + h];
    if (jj < MAXD) {
      s_lds[wid][jj*8 + h] = v;
      if (h == 0) e_lds[wid][jj] = e;
    }
    float mn = fmaxf(m, v);
    s = s * __expf(m - mn) + __expf(v - mn);
    m = mn;
  }
  #pragma unroll
  for (int d = 8; d < 64; d <<= 1) {
    float mo = __shfl_xor(m, d);
    float so = __shfl_xor(s, d);
    float mn = fmaxf(m, mo);
    s = s * __expf(m - mn) + so * __expf(mo - mn);
    m = mn;
  }
  const float rsum = 1.f / s;

  float* wout = dt ? ((float*)dout + (size_t)N_NODES*128) : scores;
  for (int jj = j; jj < deg; jj += 8) {
    float sv; int eo;
    if (jj < MAXD) {
      sv = s_lds[wid][jj*8 + h];
      eo = e_lds[wid][jj];
    } else {        // rare spill: recompute logit (bias slot still intact)
      eo = edge_sorted[start + jj];
      int src = ld_src(ei, eo, f64);
      const uint4* kr = (const uint4*)(Kd + (size_t)src*128 + h*16);
      uint4 ka = kr[0], kb = kr[1];
      sv = bfdot16(qa, qb, ka, kb) * 0.25f + scores[(size_t)eo*8 + h];
    }
    wout[(size_t)eo*8 + h] = __expf(sv - m) * rsum;
  }
}

// ------ K3b: weighted-V gather-accumulate + bf16 handoff --------------------
extern "C" __global__ __launch_bounds__(256) void node_gather_kernel(
    const int* __restrict__ ei, const int* __restrict__ offs_incl,
    const int* __restrict__ edge_sorted, const float* __restrict__ scores,
    const u16* __restrict__ Vd, void* __restrict__ dout,
    const int* __restrict__ flags)
{
  const int wid  = threadIdx.x >> 6;
  const int lane = threadIdx.x & 63;
  const int n = blockIdx.x*4 + wid;
  if (n >= N_NODES) return;
  const int f64 = flags[0], dt = flags[1];
  const int start = (n == 0) ? 0 : offs_incl[n-1];
  const int deg = offs_incl[n] - start;
  size_t slot = dt ? ((size_t)n*128 + lane) : ((size_t)n*64 + lane);
  if (deg == 0) { ((u32*)dout)[slot] = 0; return; }
  const int h2 = lane & 7;          // head for the weight this lane fetches
  const int t0 = lane >> 3;         // edge-in-chunk this lane fetches
  const int hC = lane >> 3;         // head owning output dims 2*lane, 2*lane+1
  const float* wsrc = dt ? ((const float*)dout + (size_t)N_NODES*128) : scores;
  const size_t attn_b16 = (size_t)N_NODES*128;

  float acc0 = 0.f, acc1 = 0.f;
  const int nch = (deg + 7) >> 3;
  for (int c = 0; c < nch; ++c) {
    int jj = c*8 + t0;
    float w = 0.f; int sown = 0;
    if (jj < deg) {
      int e = edge_sorted[start + jj];
      sown = ld_src(ei, e, f64);
      w = wsrc[(size_t)e*8 + h2];
      if (!dt) ((u16*)dout)[attn_b16 + (size_t)e*8 + h2] = (u16)f2bfbits(w);
    }
    int lim = deg - c*8; if (lim > 8) lim = 8;
    u32 vreg[8];
    #pragma unroll
    for (int t = 0; t < 8; ++t) {
      if (t < lim) {
        int s2 = __shfl(sown, t*8);               // wave-uniform per t
        vreg[t] = *(const u32*)(Vd + (size_t)s2*128 + lane*2);
      }
    }
    #pragma unroll
    for (int t = 0; t < 8; ++t) {
      if (t < lim) {
        float wv = __shfl(w, t*8 + hC);
        acc0 += wv * lo16(vreg[t]);
        acc1 += wv * hi16(vreg[t]);
      }
    }
  }
  ((u32*)dout)[slot] = f2bfbits(acc0) | (f2bfbits(acc1) << 16);
}

// ---------------- K4: output projection (bf16 handoff @ Wo + bo) ------------
template<int DT>
__global__ __launch_bounds__(256) void out_proj_t(
    const void* __restrict__ Wo, const void* __restrict__ bo,
    void* __restrict__ dout, const int* __restrict__ flags)
{
  if (flags[1] != DT) return;
  __shared__ float as_[64*129];
  const int tid = threadIdx.x;
  const int row0 = blockIdx.x * 64;
  {
    #pragma unroll
    for (int i = 0; i < 4; ++i) {
      int li = tid + i*256;           // 64 rows x 16 uint4 (bf16 rows)
      int r = li >> 4, q = li & 15;
      int gr = row0 + r;
      uint4 v = make_uint4(0,0,0,0);
      if (gr < N_NODES) {
        const uint4* rp = (const uint4*)((const u32*)dout + (DT ? (size_t)gr*128 : (size_t)gr*64));
        v = rp[q];
      }
      int base = r*129 + q*8;
      as_[base+0]=lo16(v.x); as_[base+1]=hi16(v.x);
      as_[base+2]=lo16(v.y); as_[base+3]=hi16(v.y);
      as_[base+4]=lo16(v.z); as_[base+5]=hi16(v.z);
      as_[base+6]=lo16(v.w); as_[base+7]=hi16(v.w);
    }
  }
  __syncthreads();
  const int cg = tid & 31;
  const int r0 = (tid >> 5) * 8;
  float acc[8][4];
  #pragma unroll
  for (int i=0;i<8;++i){ acc[i][0]=0.f; acc[i][1]=0.f; acc[i][2]=0.f; acc[i][3]=0.f; }

  for (int k = 0; k < 128; ++k) {
    float4 b;
    if (DT) {
      b = ((const float4*)Wo)[k*32 + cg];
    } else {
      uint2 t = ((const uint2*)Wo)[k*32 + cg];
      b = make_float4(lo16(t.x), hi16(t.x), lo16(t.y), hi16(t.y));
    }
    #pragma unroll
    for (int i = 0; i < 8; ++i) {
      float a = as_[(r0+i)*129 + k];
      acc[i][0] += a*b.x; acc[i][1] += a*b.y; acc[i][2] += a*b.z; acc[i][3] += a*b.w;
    }
  }
  float bb0 = ldf<DT>(bo, cg*4+0), bb1 = ldf<DT>(bo, cg*4+1);
  float bb2 = ldf<DT>(bo, cg*4+2), bb3 = ldf<DT>(bo, cg*4+3);
  #pragma unroll
  for (int i = 0; i < 8; ++i) {
    int gr = row0 + r0 + i;
    if (gr < N_NODES) {
      if (DT) {
        ((float4*)((float*)dout + (size_t)gr*128))[cg] =
            make_float4(acc[i][0]+bb0, acc[i][1]+bb1, acc[i][2]+bb2, acc[i][3]+bb3);
      } else {
        u32 p0 = f2bfbits(acc[i][0]+bb0) | (f2bfbits(acc[i][1]+bb1) << 16);
        u32 p1 = f2bfbits(acc[i][2]+bb2) | (f2bfbits(acc[i][3]+bb3) << 16);
        ((uint2*)((u16*)dout + (size_t)gr*128))[cg] = make_uint2(p0, p1);
      }
    }
  }
}

extern "C" void kernel_launch(void* const* d_in, const int* in_sizes, int n_in,
                              void* d_out, int out_size, void* d_ws, size_t ws_size,
                              hipStream_t stream)
{
  const void* x   = d_in[0];
  const int*  ei  = (const int*)d_in[1];
  const void* ea  = d_in[2];
  const void* Wq  = d_in[3];
  const void* Wk  = d_in[4];
  const void* Wv  = d_in[5];
  const void* We1 = d_in[6];
  const void* be1 = d_in[7];
  const void* We2 = d_in[8];
  const void* be2 = d_in[9];
  const void* Wo  = d_in[10];
  const void* bo  = d_in[11];

  // ws layout (83.6 MB total):
  char* ws = (char*)d_ws;
  int*   flags       = (int*)  ws;                 // 8 B (pad 4 KB)
  u16*   Vd          = (u16*)  (ws + 4096);        // 25.6 MB
  float* scores      = (float*)(ws + 25604096);    // 51.2 MB
  int*   offs        = (int*)  (ws + 76804096);    // N ints = 400 KB
  int*   bsums       = (int*)  (ws + 77204096);    // 98 ints
  int*   edge_sorted = (int*)  (ws + 77204992);    // E ints = 6.4 MB -> ends 83,604,992

  // Q/K staged in d_out's dead regions (bf16, 25.6 MB each).
  u16* Q  = (u16*)d_out;
  u16* Kd = Q + (size_t)N_NODES*128;

  detect_kernel<<<dim3(1), 64, 0, stream>>>(ei, (const u32*)x, flags);
  hipMemsetAsync(offs, 0, 400000, stream);

  qkv_gemm_t<0><<<dim3(1563,3), 256, 0, stream>>>(x, Wq, Wk, Wv, Q, Kd, Vd, flags);
  qkv_gemm_t<1><<<dim3(1563,3), 256, 0, stream>>>(x, Wq, Wk, Wv, Q, Kd, Vd, flags);

  bias_kernel_t<0><<<dim3(3125), 256, 0, stream>>>(ea, We1, be1, We2, be2, scores, flags);
  bias_kernel_t<1><<<dim3(3125), 256, 0, stream>>>(ea, We1, be1, We2, be2, scores, flags);

  hist_kernel <<<dim3(6250), 256, 0, stream>>>(ei, offs, flags);
  scan1_kernel<<<dim3(98), 1024, 0, stream>>>(offs, bsums);
  scan2_kernel<<<dim3(1), 64, 0, stream>>>(bsums, 98);
  scan3_kernel<<<dim3(98), 1024, 0, stream>>>(offs, bsums);
  fill_kernel <<<dim3(6250), 256, 0, stream>>>(ei, offs, edge_sorted, flags);

  node_score_kernel <<<dim3(25000), 256, 0, stream>>>(ei, offs, edge_sorted, scores, Q, Kd, d_out, flags);
  node_gather_kernel<<<dim3(25000), 256, 0, stream>>>(ei, offs, edge_sorted, scores, Vd, d_out, flags);

  out_proj_t<0><<<dim3(1563), 256, 0, stream>>>(Wo, bo, d_out, flags);
  out_proj_t<1><<<dim3(1563), 256, 0, stream>>>(Wo, bo, d_out, flags);
}

// Round 7
// 884.336 us; speedup vs baseline: 1.1157x; 1.1157x over previous
//
#include <hip/hip_runtime.h>

#define N_NODES 100000
#define N_EDGES 1600000
#define MAXD 64

typedef unsigned int u32;
typedef unsigned short u16;

__device__ __forceinline__ float bf2f(u16 u){ return __uint_as_float(((u32)u) << 16); }
__device__ __forceinline__ float lo16(u32 u){ return __uint_as_float(u << 16); }
__device__ __forceinline__ float hi16(u32 u){ return __uint_as_float(u & 0xffff0000u); }
__device__ __forceinline__ u32 f2bfbits(float f){
  u32 u = __float_as_uint(f);
  return (u + 0x7fffu + ((u >> 16) & 1u)) >> 16;
}

// GELU with pure-FMA erf: erf(z) = z*P(z^2), 7-term Taylor, |err|<=7e-9 for
// |z|<=0.6 (data has |z| <~ 0.53 at 6 sigma). Per-lane erff fallback for
// |z|>0.6 keeps exactness on any input (never taken here => no trans ops on
// the hot path; round-3 lesson: rcp/exp are quarter-rate, avoid them).
__device__ __forceinline__ float gelu_fast(float h){
  float z = h * 0.70710678118654752f;
  float u = z * z;
  const float k0 = 1.1283791670955126f;
  const float k1 = -0.37612638903183752f;
  const float k2 = 0.11283791670955126f;
  const float k3 = -0.026866170645131251f;
  const float k4 = 0.0052239776254421878f;
  const float k5 = -8.5483270234508528e-4f;
  const float k6 = 1.2055332981789664e-4f;
  float p = __builtin_fmaf(k6, u, k5);
  p = __builtin_fmaf(p, u, k4);
  p = __builtin_fmaf(p, u, k3);
  p = __builtin_fmaf(p, u, k2);
  p = __builtin_fmaf(p, u, k1);
  p = __builtin_fmaf(p, u, k0);
  float er = z * p;
  if (u > 0.36f) er = erff(z);      // exact tail, wave-coherently skipped
  float hh = 0.5f * h;
  return __builtin_fmaf(hh, er, hh);
}

// runtime-dt scalar load (dt=1: fp32, dt=0: bf16)
__device__ __forceinline__ float ldx(const void* p, size_t i, int dt){
  return dt ? ((const float*)p)[i] : bf2f(((const u16*)p)[i]);
}

// flags[0]: 1 if edge_index is int64, 0 if int32
// flags[1]: 1 if float tensors are fp32, 0 if bf16
__device__ __forceinline__ int ld_src(const int* ei, int e, int f64){
  return f64 ? ei[2*(size_t)e] : ei[e];
}
__device__ __forceinline__ int ld_tgt(const int* ei, int e, int f64){
  return f64 ? ei[2*((size_t)N_EDGES + (size_t)e)] : ei[(size_t)N_EDGES + e];
}

__device__ __forceinline__ float bfdot16(uint4 qa, uint4 qb, uint4 ka, uint4 kb){
  float s = 0.f;
  s += lo16(qa.x)*lo16(ka.x) + hi16(qa.x)*hi16(ka.x);
  s += lo16(qa.y)*lo16(ka.y) + hi16(qa.y)*hi16(ka.y);
  s += lo16(qa.z)*lo16(ka.z) + hi16(qa.z)*hi16(ka.z);
  s += lo16(qa.w)*lo16(ka.w) + hi16(qa.w)*hi16(ka.w);
  s += lo16(qb.x)*lo16(kb.x) + hi16(qb.x)*hi16(kb.x);
  s += lo16(qb.y)*lo16(kb.y) + hi16(qb.y)*hi16(kb.y);
  s += lo16(qb.z)*lo16(kb.z) + hi16(qb.z)*hi16(kb.z);
  s += lo16(qb.w)*lo16(kb.w) + hi16(qb.w)*hi16(kb.w);
  return s;
}

extern "C" __global__ void detect_kernel(const int* __restrict__ ei,
                                         const u32* __restrict__ xw,
                                         int* __restrict__ flags)
{
  if (blockIdx.x == 0 && threadIdx.x == 0) {
    int any = 0;
    #pragma unroll
    for (int i = 0; i < 32; ++i) any |= ei[2*i + 1];
    flags[0] = (any == 0) ? 1 : 0;
    int weird = 0;
    for (int i = 0; i < 256; ++i) {
      u32 w = xw[i];
      float a = lo16(w), b = hi16(w);
      if (!(fabsf(a) < 1024.f)) weird++;
      if (!(fabsf(b) < 1024.f)) weird++;
    }
    flags[1] = (weird > 0) ? 1 : 0;
  }
}

// ---------------- K1: QKV projection (x @ W -> bf16) ------------------------
// Merged-dt single kernel (saves a dead-variant launch). k-unrolled x4:
// 4 independent W loads in flight + ds_read_b128 A reads (stride 132 floats
// => 16B-aligned rows; the old 129 stride mis-aligned float4 stores => 3.6M
// bank conflicts). FP math order identical to the k-scalar loop (bit-exact).
extern "C" __global__ __launch_bounds__(256) void qkv_gemm(
    const void* __restrict__ x, const void* __restrict__ Wq,
    const void* __restrict__ Wk, const void* __restrict__ Wv,
    u16* __restrict__ Q, u16* __restrict__ Kd, u16* __restrict__ Vd,
    const int* __restrict__ flags)
{
  __shared__ float xs[64*132];
  const int tid = threadIdx.x;
  const int row0 = blockIdx.x * 64;
  const void* W = (blockIdx.y == 0) ? Wq : (blockIdx.y == 1) ? Wk : Wv;
  u16* Out = (blockIdx.y == 0) ? Q : (blockIdx.y == 1) ? Kd : Vd;
  const int dt = flags[1];

  if (dt) {
    const float4* xg = (const float4*)x;
    #pragma unroll
    for (int i = 0; i < 8; ++i) {
      int li = tid + i*256;           // 64 rows x 32 float4
      int r = li >> 5, c4 = li & 31;
      float4 v = make_float4(0.f,0.f,0.f,0.f);
      if (row0 + r < N_NODES) v = xg[(size_t)(row0 + r)*32 + c4];
      *(float4*)&xs[r*132 + c4*4] = v;
    }
  } else {
    const uint4* xg = (const uint4*)x;
    #pragma unroll
    for (int i = 0; i < 4; ++i) {
      int li = tid + i*256;           // 64 rows x 16 uint4
      int r = li >> 4, c8 = li & 15;
      uint4 v = make_uint4(0,0,0,0);
      if (row0 + r < N_NODES) v = xg[(size_t)(row0 + r)*16 + c8];
      int base = r*132 + c8*8;
      *(float4*)&xs[base]   = make_float4(lo16(v.x), hi16(v.x), lo16(v.y), hi16(v.y));
      *(float4*)&xs[base+4] = make_float4(lo16(v.z), hi16(v.z), lo16(v.w), hi16(v.w));
    }
  }
  __syncthreads();

  const int cg = tid & 31;
  const int r0 = (tid >> 5) * 8;
  float acc[8][4];
  #pragma unroll
  for (int i=0;i<8;++i){ acc[i][0]=0.f; acc[i][1]=0.f; acc[i][2]=0.f; acc[i][3]=0.f; }

  if (dt) {
    const float4* W4 = (const float4*)W;
    for (int k = 0; k < 128; k += 4) {
      float4 b0 = W4[(k+0)*32 + cg];
      float4 b1 = W4[(k+1)*32 + cg];
      float4 b2 = W4[(k+2)*32 + cg];
      float4 b3 = W4[(k+3)*32 + cg];
      float bb[4][4] = {{b0.x,b0.y,b0.z,b0.w},{b1.x,b1.y,b1.z,b1.w},
                        {b2.x,b2.y,b2.z,b2.w},{b3.x,b3.y,b3.z,b3.w}};
      #pragma unroll
      for (int i = 0; i < 8; ++i) {
        float4 av = *(const float4*)&xs[(r0+i)*132 + k];
        #pragma unroll
        for (int c = 0; c < 4; ++c) {
          float t = acc[i][c];
          t = __builtin_fmaf(av.x, bb[0][c], t);
          t = __builtin_fmaf(av.y, bb[1][c], t);
          t = __builtin_fmaf(av.z, bb[2][c], t);
          t = __builtin_fmaf(av.w, bb[3][c], t);
          acc[i][c] = t;
        }
      }
    }
  } else {
    const uint2* W2 = (const uint2*)W;
    for (int k = 0; k < 128; k += 4) {
      uint2 t0 = W2[(k+0)*32 + cg];
      uint2 t1 = W2[(k+1)*32 + cg];
      uint2 t2 = W2[(k+2)*32 + cg];
      uint2 t3 = W2[(k+3)*32 + cg];
      float bb[4][4] = {{lo16(t0.x),hi16(t0.x),lo16(t0.y),hi16(t0.y)},
                        {lo16(t1.x),hi16(t1.x),lo16(t1.y),hi16(t1.y)},
                        {lo16(t2.x),hi16(t2.x),lo16(t2.y),hi16(t2.y)},
                        {lo16(t3.x),hi16(t3.x),lo16(t3.y),hi16(t3.y)}};
      #pragma unroll
      for (int i = 0; i < 8; ++i) {
        float4 av = *(const float4*)&xs[(r0+i)*132 + k];
        #pragma unroll
        for (int c = 0; c < 4; ++c) {
          float t = acc[i][c];
          t = __builtin_fmaf(av.x, bb[0][c], t);
          t = __builtin_fmaf(av.y, bb[1][c], t);
          t = __builtin_fmaf(av.z, bb[2][c], t);
          t = __builtin_fmaf(av.w, bb[3][c], t);
          acc[i][c] = t;
        }
      }
    }
  }

  #pragma unroll
  for (int i = 0; i < 8; ++i) {
    int gr = row0 + r0 + i;
    if (gr < N_NODES) {
      u32 p0 = f2bfbits(acc[i][0]) | (f2bfbits(acc[i][1]) << 16);
      u32 p1 = f2bfbits(acc[i][2]) | (f2bfbits(acc[i][3]) << 16);
      ((uint2*)(Out + (size_t)gr*128))[cg] = make_uint2(p0, p1);
    }
  }
}

// -------- K2a: per-edge MLP bias -> scores, + fused CSR histogram -----------
// 2 edges/thread (round-4: no spills, VALUBusy ~100%). Merged-dt. The tgt
// histogram (formerly hist_kernel) rides along: its scattered loads/atomics
// use memory slots this VALU-bound kernel leaves idle; saves one launch.
extern "C" __global__ __launch_bounds__(256) void bias_kernel(
    const void* __restrict__ ea,
    const void* __restrict__ We1, const void* __restrict__ be1,
    const void* __restrict__ We2, const void* __restrict__ be2,
    float* __restrict__ scores, const int* __restrict__ ei,
    int* __restrict__ offs, const int* __restrict__ flags)
{
  __shared__ __align__(16) float wpk[128][16]; // {be1, We1[0..5][j], pad, We2[j][0..7]}
  __shared__ float b2s[8];
  const int tid = threadIdx.x;
  const int dt = flags[1];
  if (tid < 128) {
    int j = tid;
    wpk[j][0] = ldx(be1, j, dt);
    #pragma unroll
    for (int d = 0; d < 6; ++d) wpk[j][1+d] = ldx(We1, d*128 + j, dt);
    wpk[j][7] = 0.f;
    #pragma unroll
    for (int h = 0; h < 8; ++h) wpk[j][8+h] = ldx(We2, j*8 + h, dt);
  }
  if (tid < 8) b2s[tid] = ldx(be2, tid, dt);
  __syncthreads();

  const int gid = blockIdx.x * 256 + tid;
  if (gid >= N_EDGES/2) return;
  const int e0 = gid * 2;

  // fused histogram: issue tgt loads early, atomics at the end
  const int f64 = flags[0];
  int tg0 = ld_tgt(ei, e0, f64);
  int tg1 = ld_tgt(ei, e0+1, f64);

  float a[12];
  if (dt) {
    const float4* eg = (const float4*)ea + (size_t)gid*3;   // 2 edges = 12 floats
    float4 v0 = eg[0], v1 = eg[1], v2 = eg[2];
    a[0]=v0.x; a[1]=v0.y; a[2]=v0.z; a[3]=v0.w;
    a[4]=v1.x; a[5]=v1.y; a[6]=v1.z; a[7]=v1.w;
    a[8]=v2.x; a[9]=v2.y; a[10]=v2.z; a[11]=v2.w;
  } else {
    const uint2* eg = (const uint2*)ea + (size_t)gid*3;     // 2 edges = 12 bf16 = 24B
    uint2 v0 = eg[0], v1 = eg[1], v2 = eg[2];
    u32 d[6] = {v0.x, v0.y, v1.x, v1.y, v2.x, v2.y};
    #pragma unroll
    for (int idx = 0; idx < 12; ++idx)
      a[idx] = (idx & 1) ? hi16(d[idx >> 1]) : lo16(d[idx >> 1]);
  }

  float bias[2][8];
  #pragma unroll
  for (int t=0;t<2;++t)
    #pragma unroll
    for (int h=0;h<8;++h) bias[t][h] = b2s[h];

  for (int j = 0; j < 128; ++j) {
    const float4* wp = (const float4*)wpk[j];
    float4 p0 = wp[0], p1 = wp[1], p2 = wp[2], p3 = wp[3];
    #pragma unroll
    for (int t = 0; t < 2; ++t) {
      float h = p0.x + a[t*6+0]*p0.y + a[t*6+1]*p0.z + a[t*6+2]*p0.w
                     + a[t*6+3]*p1.x + a[t*6+4]*p1.y + a[t*6+5]*p1.z;
      float g = gelu_fast(h);
      bias[t][0] += g*p2.x; bias[t][1] += g*p2.y; bias[t][2] += g*p2.z; bias[t][3] += g*p2.w;
      bias[t][4] += g*p3.x; bias[t][5] += g*p3.y; bias[t][6] += g*p3.z; bias[t][7] += g*p3.w;
    }
  }

  #pragma unroll
  for (int t = 0; t < 2; ++t) {
    float4* so = (float4*)(scores + (size_t)(e0 + t)*8);
    so[0] = make_float4(bias[t][0],bias[t][1],bias[t][2],bias[t][3]);
    so[1] = make_float4(bias[t][4],bias[t][5],bias[t][6],bias[t][7]);
  }

  atomicAdd(&offs[tg0], 1);
  atomicAdd(&offs[tg1], 1);
}

// ---------------- CSR build: scan (2 kernels), fill -------------------------
extern "C" __global__ __launch_bounds__(1024) void scan1_kernel(
    int* __restrict__ offs, int* __restrict__ bsums)
{
  __shared__ int tmp[1024];
  int tid = threadIdx.x;
  int i = blockIdx.x*1024 + tid;
  int v = (i < N_NODES) ? offs[i] : 0;
  tmp[tid] = v;
  __syncthreads();
  for (int d = 1; d < 1024; d <<= 1) {
    int t = (tid >= d) ? tmp[tid-d] : 0;
    __syncthreads();
    tmp[tid] += t;
    __syncthreads();
  }
  if (i < N_NODES) offs[i] = tmp[tid] - v;   // block-exclusive
  if (tid == 1023) bsums[blockIdx.x] = tmp[1023];
}

// scan3 with inline reduction of preceding block sums (absorbs old scan2):
// 98 blocks, each sums bsums[0..blockIdx) in parallel via LDS tree.
extern "C" __global__ __launch_bounds__(1024) void scan3_kernel(
    int* __restrict__ offs, const int* __restrict__ bsums)
{
  __shared__ int red[128];
  int tid = threadIdx.x;
  if (tid < 128) red[tid] = (tid < blockIdx.x) ? bsums[tid] : 0; // blockIdx < 98 < 128
  __syncthreads();
  #pragma unroll
  for (int s = 64; s > 0; s >>= 1) {
    if (tid < s) red[tid] += red[tid + s];
    __syncthreads();
  }
  int base = red[0];
  int i = blockIdx.x*1024 + tid;
  if (i < N_NODES) offs[i] += base;
}

extern "C" __global__ __launch_bounds__(256) void fill_kernel(
    const int* __restrict__ ei, int* __restrict__ offs,
    int* __restrict__ edge_sorted, const int* __restrict__ flags)
{
  int e = blockIdx.x*256 + threadIdx.x;
  if (e >= N_EDGES) return;
  int t = ld_tgt(ei, e, flags[0]);
  int p = atomicAdd(&offs[t], 1);
  edge_sorted[p] = e;
}

// ------ K3a: fused QK-dot + bias + online softmax + weight emit -------------
extern "C" __global__ __launch_bounds__(256) void node_score_kernel(
    const int* __restrict__ ei, const int* __restrict__ offs_incl,
    const int* __restrict__ edge_sorted, float* __restrict__ scores,
    const u16* __restrict__ Q, const u16* __restrict__ Kd,
    void* __restrict__ dout, const int* __restrict__ flags)
{
  __shared__ float s_lds[4][MAXD*8];
  __shared__ int   e_lds[4][MAXD];
  const int wid  = threadIdx.x >> 6;
  const int lane = threadIdx.x & 63;
  const int n = blockIdx.x*4 + wid;
  if (n >= N_NODES) return;
  const int f64 = flags[0], dt = flags[1];
  const int start = (n == 0) ? 0 : offs_incl[n-1];
  const int deg = offs_incl[n] - start;
  if (deg == 0) return;
  const int h = lane & 7, j = lane >> 3;

  // Q fragment for head h (32B, broadcast among the 8 lanes sharing h)
  const uint4* qr = (const uint4*)(Q + (size_t)n*128 + h*16);
  uint4 qa = qr[0], qb = qr[1];

  float m = -3.0e38f, s = 0.f;
  for (int jj = j; jj < deg; jj += 8) {
    int e = edge_sorted[start + jj];
    int src = ld_src(ei, e, f64);
    const uint4* kr = (const uint4*)(Kd + (size_t)src*128 + h*16);
    uint4 ka = kr[0], kb = kr[1];
    float v = bfdot16(qa, qb, ka, kb) * 0.25f + scores[(size_t)e*8 + h];
    if (jj < MAXD) {
      s_lds[wid][jj*8 + h] = v;
      if (h == 0) e_lds[wid][jj] = e;
    }
    float mn = fmaxf(m, v);
    s = s * __expf(m - mn) + __expf(v - mn);
    m = mn;
  }
  #pragma unroll
  for (int d = 8; d < 64; d <<= 1) {
    float mo = __shfl_xor(m, d);
    float so = __shfl_xor(s, d);
    float mn = fmaxf(m, mo);
    s = s * __expf(m - mn) + so * __expf(mo - mn);
    m = mn;
  }
  const float rsum = 1.f / s;

  float* wout = dt ? ((float*)dout + (size_t)N_NODES*128) : scores;
  for (int jj = j; jj < deg; jj += 8) {
    float sv; int eo;
    if (jj < MAXD) {
      sv = s_lds[wid][jj*8 + h];
      eo = e_lds[wid][jj];
    } else {        // rare spill: recompute logit (bias slot still intact)
      eo = edge_sorted[start + jj];
      int src = ld_src(ei, eo, f64);
      const uint4* kr = (const uint4*)(Kd + (size_t)src*128 + h*16);
      uint4 ka = kr[0], kb = kr[1];
      sv = bfdot16(qa, qb, ka, kb) * 0.25f + scores[(size_t)eo*8 + h];
    }
    wout[(size_t)eo*8 + h] = __expf(sv - m) * rsum;
  }
}

// ------ K3b: weighted-V gather-accumulate + bf16 handoff --------------------
extern "C" __global__ __launch_bounds__(256) void node_gather_kernel(
    const int* __restrict__ ei, const int* __restrict__ offs_incl,
    const int* __restrict__ edge_sorted, const float* __restrict__ scores,
    const u16* __restrict__ Vd, void* __restrict__ dout,
    const int* __restrict__ flags)
{
  const int wid  = threadIdx.x >> 6;
  const int lane = threadIdx.x & 63;
  const int n = blockIdx.x*4 + wid;
  if (n >= N_NODES) return;
  const int f64 = flags[0], dt = flags[1];
  const int start = (n == 0) ? 0 : offs_incl[n-1];
  const int deg = offs_incl[n] - start;
  size_t slot = dt ? ((size_t)n*128 + lane) : ((size_t)n*64 + lane);
  if (deg == 0) { ((u32*)dout)[slot] = 0; return; }
  const int h2 = lane & 7;          // head for the weight this lane fetches
  const int t0 = lane >> 3;         // edge-in-chunk this lane fetches
  const int hC = lane >> 3;         // head owning output dims 2*lane, 2*lane+1
  const float* wsrc = dt ? ((const float*)dout + (size_t)N_NODES*128) : scores;
  const size_t attn_b16 = (size_t)N_NODES*128;

  float acc0 = 0.f, acc1 = 0.f;
  const int nch = (deg + 7) >> 3;
  for (int c = 0; c < nch; ++c) {
    int jj = c*8 + t0;
    float w = 0.f; int sown = 0;
    if (jj < deg) {
      int e = edge_sorted[start + jj];
      sown = ld_src(ei, e, f64);
      w = wsrc[(size_t)e*8 + h2];
      if (!dt) ((u16*)dout)[attn_b16 + (size_t)e*8 + h2] = (u16)f2bfbits(w);
    }
    int lim = deg - c*8; if (lim > 8) lim = 8;
    u32 vreg[8];
    #pragma unroll
    for (int t = 0; t < 8; ++t) {
      if (t < lim) {
        int s2 = __shfl(sown, t*8);               // wave-uniform per t
        vreg[t] = *(const u32*)(Vd + (size_t)s2*128 + lane*2);
      }
    }
    #pragma unroll
    for (int t = 0; t < 8; ++t) {
      if (t < lim) {
        float wv = __shfl(w, t*8 + hC);
        acc0 += wv * lo16(vreg[t]);
        acc1 += wv * hi16(vreg[t]);
      }
    }
  }
  ((u32*)dout)[slot] = f2bfbits(acc0) | (f2bfbits(acc1) << 16);
}

// ---------------- K4: output projection (bf16 handoff @ Wo + bo) ------------
// Merged-dt; same k-unroll x4 + 132-stride alignment as qkv_gemm.
extern "C" __global__ __launch_bounds__(256) void out_proj(
    const void* __restrict__ Wo, const void* __restrict__ bo,
    void* __restrict__ dout, const int* __restrict__ flags)
{
  __shared__ float as_[64*132];
  const int tid = threadIdx.x;
  const int row0 = blockIdx.x * 64;
  const int dt = flags[1];
  {
    #pragma unroll
    for (int i = 0; i < 4; ++i) {
      int li = tid + i*256;           // 64 rows x 16 uint4 (bf16 rows)
      int r = li >> 4, q = li & 15;
      int gr = row0 + r;
      uint4 v = make_uint4(0,0,0,0);
      if (gr < N_NODES) {
        const uint4* rp = (const uint4*)((const u32*)dout + (dt ? (size_t)gr*128 : (size_t)gr*64));
        v = rp[q];
      }
      int base = r*132 + q*8;
      *(float4*)&as_[base]   = make_float4(lo16(v.x), hi16(v.x), lo16(v.y), hi16(v.y));
      *(float4*)&as_[base+4] = make_float4(lo16(v.z), hi16(v.z), lo16(v.w), hi16(v.w));
    }
  }
  __syncthreads();
  const int cg = tid & 31;
  const int r0 = (tid >> 5) * 8;
  float acc[8][4];
  #pragma unroll
  for (int i=0;i<8;++i){ acc[i][0]=0.f; acc[i][1]=0.f; acc[i][2]=0.f; acc[i][3]=0.f; }

  if (dt) {
    const float4* W4 = (const float4*)Wo;
    for (int k = 0; k < 128; k += 4) {
      float4 b0 = W4[(k+0)*32 + cg];
      float4 b1 = W4[(k+1)*32 + cg];
      float4 b2 = W4[(k+2)*32 + cg];
      float4 b3 = W4[(k+3)*32 + cg];
      float bb[4][4] = {{b0.x,b0.y,b0.z,b0.w},{b1.x,b1.y,b1.z,b1.w},
                        {b2.x,b2.y,b2.z,b2.w},{b3.x,b3.y,b3.z,b3.w}};
      #pragma unroll
      for (int i = 0; i < 8; ++i) {
        float4 av = *(const float4*)&as_[(r0+i)*132 + k];
        #pragma unroll
        for (int c = 0; c < 4; ++c) {
          float t = acc[i][c];
          t = __builtin_fmaf(av.x, bb[0][c], t);
          t = __builtin_fmaf(av.y, bb[1][c], t);
          t = __builtin_fmaf(av.z, bb[2][c], t);
          t = __builtin_fmaf(av.w, bb[3][c], t);
          acc[i][c] = t;
        }
      }
    }
  } else {
    const uint2* W2 = (const uint2*)Wo;
    for (int k = 0; k < 128; k += 4) {
      uint2 t0 = W2[(k+0)*32 + cg];
      uint2 t1 = W2[(k+1)*32 + cg];
      uint2 t2 = W2[(k+2)*32 + cg];
      uint2 t3 = W2[(k+3)*32 + cg];
      float bb[4][4] = {{lo16(t0.x),hi16(t0.x),lo16(t0.y),hi16(t0.y)},
                        {lo16(t1.x),hi16(t1.x),lo16(t1.y),hi16(t1.y)},
                        {lo16(t2.x),hi16(t2.x),lo16(t2.y),hi16(t2.y)},
                        {lo16(t3.x),hi16(t3.x),lo16(t3.y),hi16(t3.y)}};
      #pragma unroll
      for (int i = 0; i < 8; ++i) {
        float4 av = *(const float4*)&as_[(r0+i)*132 + k];
        #pragma unroll
        for (int c = 0; c < 4; ++c) {
          float t = acc[i][c];
          t = __builtin_fmaf(av.x, bb[0][c], t);
          t = __builtin_fmaf(av.y, bb[1][c], t);
          t = __builtin_fmaf(av.z, bb[2][c], t);
          t = __builtin_fmaf(av.w, bb[3][c], t);
          acc[i][c] = t;
        }
      }
    }
  }

  float bb0 = ldx(bo, cg*4+0, dt), bb1 = ldx(bo, cg*4+1, dt);
  float bb2 = ldx(bo, cg*4+2, dt), bb3 = ldx(bo, cg*4+3, dt);
  #pragma unroll
  for (int i = 0; i < 8; ++i) {
    int gr = row0 + r0 + i;
    if (gr < N_NODES) {
      if (dt) {
        ((float4*)((float*)dout + (size_t)gr*128))[cg] =
            make_float4(acc[i][0]+bb0, acc[i][1]+bb1, acc[i][2]+bb2, acc[i][3]+bb3);
      } else {
        u32 p0 = f2bfbits(acc[i][0]+bb0) | (f2bfbits(acc[i][1]+bb1) << 16);
        u32 p1 = f2bfbits(acc[i][2]+bb2) | (f2bfbits(acc[i][3]+bb3) << 16);
        ((uint2*)((u16*)dout + (size_t)gr*128))[cg] = make_uint2(p0, p1);
      }
    }
  }
}

extern "C" void kernel_launch(void* const* d_in, const int* in_sizes, int n_in,
                              void* d_out, int out_size, void* d_ws, size_t ws_size,
                              hipStream_t stream)
{
  const void* x   = d_in[0];
  const int*  ei  = (const int*)d_in[1];
  const void* ea  = d_in[2];
  const void* Wq  = d_in[3];
  const void* Wk  = d_in[4];
  const void* Wv  = d_in[5];
  const void* We1 = d_in[6];
  const void* be1 = d_in[7];
  const void* We2 = d_in[8];
  const void* be2 = d_in[9];
  const void* Wo  = d_in[10];
  const void* bo  = d_in[11];

  // ws layout (83.6 MB total):
  char* ws = (char*)d_ws;
  int*   flags       = (int*)  ws;                 // 8 B (pad 4 KB)
  u16*   Vd          = (u16*)  (ws + 4096);        // 25.6 MB
  float* scores      = (float*)(ws + 25604096);    // 51.2 MB
  int*   offs        = (int*)  (ws + 76804096);    // N ints = 400 KB
  int*   bsums       = (int*)  (ws + 77204096);    // 98 ints
  int*   edge_sorted = (int*)  (ws + 77204992);    // E ints = 6.4 MB -> ends 83,604,992

  // Q/K staged in d_out's dead regions (bf16, 25.6 MB each).
  u16* Q  = (u16*)d_out;
  u16* Kd = Q + (size_t)N_NODES*128;

  detect_kernel<<<dim3(1), 64, 0, stream>>>(ei, (const u32*)x, flags);
  hipMemsetAsync(offs, 0, 400000, stream);

  qkv_gemm<<<dim3(1563,3), 256, 0, stream>>>(x, Wq, Wk, Wv, Q, Kd, Vd, flags);

  bias_kernel<<<dim3(3125), 256, 0, stream>>>(ea, We1, be1, We2, be2, scores, ei, offs, flags);

  scan1_kernel<<<dim3(98), 1024, 0, stream>>>(offs, bsums);
  scan3_kernel<<<dim3(98), 1024, 0, stream>>>(offs, bsums);
  fill_kernel <<<dim3(6250), 256, 0, stream>>>(ei, offs, edge_sorted, flags);

  node_score_kernel <<<dim3(25000), 256, 0, stream>>>(ei, offs, edge_sorted, scores, Q, Kd, d_out, flags);
  node_gather_kernel<<<dim3(25000), 256, 0, stream>>>(ei, offs, edge_sorted, scores, Vd, d_out, flags);

  out_proj<<<dim3(1563), 256, 0, stream>>>(Wo, bo, d_out, flags);
}